// Round 2
// baseline (764.213 us; speedup 1.0000x reference)
//
#include <hip/hip_runtime.h>
#include <math.h>

#define H   256
#define H2  512
#define FRONTIER_BONUS 0.5f
#define LN_EPS   1e-5f
#define F32_EPS  1.1920929e-07f   // jnp.finfo(float32).eps

typedef float v4f __attribute__((ext_vector_type(4)));

// ---------------------------------------------------------------------------
// Wave-level butterfly reductions (6 shfl) + 4-slot LDS combine: 2 barriers
// per block reduction instead of the 8-round shared-memory tree.
// ---------------------------------------------------------------------------
__device__ __forceinline__ float wave_sum(float p) {
    #pragma unroll
    for (int off = 1; off < 64; off <<= 1) p += __shfl_xor(p, off, 64);
    return p;   // all lanes hold the total
}
__device__ __forceinline__ float wave_max(float p) {
    #pragma unroll
    for (int off = 1; off < 64; off <<= 1) p = fmaxf(p, __shfl_xor(p, off, 64));
    return p;
}
__device__ __forceinline__ float block_sum_256(float v, float* sb4) {
    float w = wave_sum(v);
    __syncthreads();                       // protect sb4 from prior readers
    if ((threadIdx.x & 63) == 0) sb4[threadIdx.x >> 6] = w;
    __syncthreads();
    return sb4[0] + sb4[1] + sb4[2] + sb4[3];
}
__device__ __forceinline__ float block_max_256(float v, float* sb4) {
    float w = wave_max(v);
    __syncthreads();
    if ((threadIdx.x & 63) == 0) sb4[threadIdx.x >> 6] = w;
    __syncthreads();
    return fmaxf(fmaxf(sb4[0], sb4[1]), fmaxf(sb4[2], sb4[3]));
}

// ---------------------------------------------------------------------------
// Prologue (G+1 blocks):
//   block g<G : pooled_sum[g,:]=0 ; qatt[g] = q[g,:] . (att_vec @ W_query)
//   block G   : u = att_vec @ W_edge
// ---------------------------------------------------------------------------
__global__ __launch_bounds__(256) void k_pro(const float* __restrict__ W_edge,
                                             const float* __restrict__ W_query,
                                             const float* __restrict__ att_vec,
                                             const float* __restrict__ q,
                                             float* __restrict__ u,
                                             float* __restrict__ qatt,
                                             float* __restrict__ pooled_sum,
                                             int G) {
    __shared__ float sb4[4];
    int g = blockIdx.x, tid = threadIdx.x;
    if (g == G) {                       // u = att_vec @ W_edge
        float acc = 0.f;
        #pragma unroll 8
        for (int i = 0; i < H; ++i) acc += att_vec[i] * W_edge[i * H + tid];
        u[tid] = acc;
        return;
    }
    pooled_sum[(size_t)g * H + tid] = 0.f;
    float wv = 0.f;
    #pragma unroll 8
    for (int i = 0; i < H; ++i) wv += att_vec[i] * W_query[i * H + tid];
    float v = q[(size_t)g * H + tid] * wv;
    float s = block_sum_256(v, sb4);
    if (tid == 0) qatt[g] = s;
}

// ---------------------------------------------------------------------------
// Main pass: one streaming read of edge_tokens (512 MB). One wave per
// contiguous edge chunk; branch-free runs of <=64 edges via __ballot;
// butterfly shfl dot; pooled accumulator flushed at graph boundaries.
// BW-bound with ~90% issue slack -> the first G+1 waves also compute the
// segment boundaries (binary search) for free, removing the 17-step
// dependent-load chain from the head of every k_epi block.
// ---------------------------------------------------------------------------
__global__ __launch_bounds__(256) void k_main(const float* __restrict__ edge_tokens,
                                              const int*   __restrict__ edge_batch,
                                              const int*   __restrict__ selected,
                                              const float* __restrict__ u,
                                              const float* __restrict__ qatt,
                                              float* __restrict__ att_raw,
                                              float* __restrict__ pooled_sum,
                                              int*   __restrict__ row_ofs,
                                              int E, int G, int chunk) {
    int wave = (blockIdx.x * blockDim.x + threadIdx.x) >> 6;
    int lane = threadIdx.x & 63;

    if (lane == 0 && wave <= G) {          // hoisted segment-boundary search
        int lo = 0, hi = E;
        while (lo < hi) { int mm = (lo + hi) >> 1;
                          if (edge_batch[mm] < wave) lo = mm + 1; else hi = mm; }
        row_ofs[wave] = lo;
    }

    int e0 = wave * chunk;
    if (e0 >= E) return;
    int e1 = e0 + chunk; if (e1 > E) e1 = E;

    const v4f u4 = ((const v4f*)u)[lane];
    const v4f* et = (const v4f*)edge_tokens;
    v4f acc = (v4f)(0.f);
    int cur = edge_batch[e0];

    int e = e0;
    while (e < e1) {
        int n = e1 - e; if (n > 64) n = 64;
        int idx = e + ((lane < n) ? lane : (n - 1));
        int gb  = edge_batch[idx];                 // coalesced window load
        int sel = selected[idx];
        int g0  = __shfl(gb, 0, 64);               // wave-uniform graph id
        unsigned long long diff = __ballot(gb != g0);
        int run = n;
        if (diff) { int f = (int)__ffsll(diff) - 1; if (f < run) run = f; }

        if (g0 != cur) {                           // flush pooled accumulator
            float* dst = pooled_sum + (size_t)cur * H + lane * 4;
            atomicAdd(dst + 0, acc.x); atomicAdd(dst + 1, acc.y);
            atomicAdd(dst + 2, acc.z); atomicAdd(dst + 3, acc.w);
            acc = (v4f)(0.f);
            cur = g0;
        }
        float qa = qatt[g0];                       // wave-uniform
        float my_att = 0.f;

        #pragma unroll 4
        for (int i = 0; i < run; ++i) {
            v4f t = __builtin_nontemporal_load(&et[(size_t)(e + i) * 64 + lane]);
            acc += t;
            float p = fmaf(t.x, u4.x, fmaf(t.y, u4.y, fmaf(t.z, u4.z, t.w * u4.w)));
            p = wave_sum(p);
            if (i == lane) my_att = p;             // lane i keeps edge e+i
        }

        if (lane < run) {                          // coalesced att_raw store
            float a = my_att + qa;
            a = (a > 0.f) ? a : 0.2f * a;          // LeakyReLU(0.2)
            if (sel == 0) a += FRONTIER_BONUS;
            att_raw[e + lane] = a;
        }
        e += run;
    }
    float* dst = pooled_sum + (size_t)cur * H + lane * 4;
    atomicAdd(dst + 0, acc.x); atomicAdd(dst + 1, acc.y);
    atomicAdd(dst + 2, acc.z); atomicAdd(dst + 3, acc.w);
}

// ---------------------------------------------------------------------------
// Epilogue (G blocks): segment softmax -> edge_logits, then
// pooled = (pooled_sum @ W_edge.T)/cnt, LayerNorm(concat) -> W1 -> GELU -> W2.
// Segment bounds come precomputed from k_main (row_ofs).
// ---------------------------------------------------------------------------
__global__ __launch_bounds__(256) void k_epi(const int*   __restrict__ row_ofs,
                                             const int*   __restrict__ selected,
                                             const float* __restrict__ att_raw,
                                             const float* __restrict__ pooled_sum,
                                             const float* __restrict__ q,
                                             const float* __restrict__ W_edge,
                                             const float* __restrict__ ln_g,
                                             const float* __restrict__ ln_b,
                                             const float* __restrict__ W1,
                                             const float* __restrict__ b1,
                                             const float* __restrict__ W2,
                                             const float* __restrict__ b2,
                                             float* __restrict__ edge_logits,
                                             float* __restrict__ pooled_out,
                                             float* __restrict__ stop_out) {
    __shared__ __align__(16) float sS[H];
    __shared__ __align__(16) float sP[H];
    __shared__ __align__(16) float sxn[H2];
    __shared__ __align__(16) float sgk[H];
    __shared__ float sb4[4];
    int g = blockIdx.x, tid = threadIdx.x;
    int lane = tid & 63, wv = tid >> 6;            // 4 waves

    int s = row_ofs[g], t = row_ofs[g + 1];        // precomputed bounds
    sS[tid] = pooled_sum[(size_t)g * H + tid];

    // ---- segment softmax -> edge_logits
    float m = -INFINITY;
    for (int e = s + tid; e < t; e += 256) m = fmaxf(m, att_raw[e]);
    m = block_max_256(m, sb4);                     // barrier also publishes sS

    float ss = 0.f;
    for (int e = s + tid; e < t; e += 256)
        if (selected[e] == 0) ss += expf(att_raw[e] - m);
    ss = block_sum_256(ss, sb4);
    float denom = fmaxf(ss, F32_EPS);

    for (int e = s + tid; e < t; e += 256) {
        float ex = (selected[e] == 0) ? expf(att_raw[e] - m) : 0.f;
        edge_logits[e] = logf(fmaxf(ex / denom, F32_EPS));
    }

    // ---- pooled GEMV: P[i] = (sS . W_edge[i,:]) / max(cnt,1)
    int   cnt = t - s;
    float inv = 1.f / (float)(cnt > 1 ? cnt : 1);
    v4f s4 = ((const v4f*)sS)[lane];
    #pragma unroll 4
    for (int r = 0; r < 64; ++r) {
        int i = wv * 64 + r;
        v4f w4 = ((const v4f*)(W_edge + (size_t)i * H))[lane];
        float p = fmaf(w4.x, s4.x, fmaf(w4.y, s4.y, fmaf(w4.z, s4.z, w4.w * s4.w)));
        p = wave_sum(p);
        if (lane == 0) sP[i] = p * inv;
    }
    __syncthreads();
    float P = sP[tid];
    pooled_out[(size_t)g * H + tid] = P;

    // ---- LayerNorm over concat(P, q) (512 elems, 2 per thread)
    float x1 = q[(size_t)g * H + tid];
    float mu  = block_sum_256(P + x1, sb4) * (1.f / (float)H2);
    float d0 = P - mu, d1 = x1 - mu;
    float var = block_sum_256(d0 * d0 + d1 * d1, sb4) * (1.f / (float)H2);
    float rstd = rsqrtf(var + LN_EPS);
    sxn[tid]     = d0 * rstd * ln_g[tid]     + ln_b[tid];
    sxn[tid + H] = d1 * rstd * ln_g[tid + H] + ln_b[tid + H];
    __syncthreads();

    // ---- h1[k] = gelu(xn . W1[k,:] + b1[k]); stop = sum_k h1[k]*W2[k] + b2
    v4f xa = ((const v4f*)sxn)[lane];
    v4f xb = ((const v4f*)sxn)[lane + 64];
    #pragma unroll 4
    for (int r = 0; r < 64; ++r) {
        int k = wv * 64 + r;
        const v4f* w1r = (const v4f*)(W1 + (size_t)k * H2);
        v4f a0 = w1r[lane], a1 = w1r[lane + 64];
        float p = fmaf(a0.x, xa.x, fmaf(a0.y, xa.y, fmaf(a0.z, xa.z, a0.w * xa.w)))
                + fmaf(a1.x, xb.x, fmaf(a1.y, xb.y, fmaf(a1.z, xb.z, a1.w * xb.w)));
        p = wave_sum(p);
        if (lane == 0) {
            float a = p + b1[k];
            float ge = 0.5f * a * (1.f + erff(a * 0.70710678118654752f));
            sgk[k] = ge * W2[k];
        }
    }
    __syncthreads();
    float tot = block_sum_256(sgk[tid], sb4);
    if (tid == 0) stop_out[g] = tot + b2[0];
}

// ---------------------------------------------------------------------------
extern "C" void kernel_launch(void* const* d_in, const int* in_sizes, int n_in,
                              void* d_out, int out_size, void* d_ws, size_t ws_size,
                              hipStream_t stream) {
    const float* edge_tokens     = (const float*)d_in[0];
    const float* question_tokens = (const float*)d_in[1];
    const int*   edge_batch      = (const int*)  d_in[2];
    const int*   selected        = (const int*)  d_in[3];
    const float* W_edge          = (const float*)d_in[4];
    const float* W_query         = (const float*)d_in[5];
    const float* att_vec         = (const float*)d_in[6];
    const float* ln_g            = (const float*)d_in[7];
    const float* ln_b            = (const float*)d_in[8];
    const float* W1              = (const float*)d_in[9];
    const float* b1              = (const float*)d_in[10];
    const float* W2              = (const float*)d_in[11];
    const float* b2              = (const float*)d_in[12];

    const int E = in_sizes[2];          // 500000
    const int G = in_sizes[1] / H;      // 256

    float* out         = (float*)d_out;
    float* edge_logits = out;           // [E]
    float* stop_out    = out + E;       // [G]
    float* pooled_out  = out + E + G;   // [G*H]

    float* ws         = (float*)d_ws;
    float* att_raw    = ws;                              // E
    float* pooled_sum = ws + E;                          // G*H
    float* u          = pooled_sum + (size_t)G * H;      // H
    float* qatt       = u + H;                           // G
    int*   row_ofs    = (int*)(qatt + G);                // G+1

    k_pro<<<G + 1, 256, 0, stream>>>(W_edge, W_query, att_vec, question_tokens,
                                     u, qatt, pooled_sum, G);

    const int nblocks = 2048;                    // 8192 waves, contiguous chunks
    const int waves   = nblocks * (256 / 64);
    const int chunk   = (E + waves - 1) / waves;
    k_main<<<nblocks, 256, 0, stream>>>(edge_tokens, edge_batch, selected,
                                        u, qatt, att_raw, pooled_sum, row_ofs,
                                        E, G, chunk);

    k_epi<<<G, 256, 0, stream>>>(row_ofs, selected, att_raw, pooled_sum,
                                 question_tokens, W_edge, ln_g, ln_b,
                                 W1, b1, W2, b2,
                                 edge_logits, pooled_out, stop_out);
}